// Round 2
// baseline (620.609 us; speedup 1.0000x reference)
//
#include <hip/hip_runtime.h>

// Problem constants (fixed by the reference)
#define Bn 2
#define Nn 256
#define Mn 512
#define Cn 256
#define Hn 8
#define FHn 128           // F/2
#define MT 64             // m-tile size in fused kernel
#define SCALE_ 0.17677669529663687f   // Dh^-0.5, Dh=32

typedef short bf16x8 __attribute__((ext_vector_type(8)));
typedef float f32x4 __attribute__((ext_vector_type(4)));

static __device__ __forceinline__ float b2f(short s) {
    unsigned u = ((unsigned)(unsigned short)s) << 16;
    return __builtin_bit_cast(float, u);
}
static __device__ __forceinline__ short f2b(float f) {   // RNE f32->bf16
    unsigned u = __builtin_bit_cast(unsigned, f);
    u += 0x7fffu + ((u >> 16) & 1u);
    return (short)(u >> 16);
}

// ---- convert W1/W2 (f32 -> bf16), 65536 elems each ----
__global__ void convert_w(const float* __restrict__ W1, const float* __restrict__ W2,
                          short* __restrict__ W1b, short* __restrict__ W2b) {
    int i = blockIdx.x * 256 + threadIdx.x;
    W1b[i] = f2b(W1[i]);
    W2b[i] = f2b(W2[i]);
}

// ---- generic row-linear: out[r][c] = sum_k A[r][k]*W[c][k] (+bias) (+res) ----
// 8 rows per block, 256 threads (thread = output channel c). K = Cn = 256.
__global__ __launch_bounds__(256) void linear8(
        const float* __restrict__ A, const float* __restrict__ W,
        const float* __restrict__ bias, const float* __restrict__ res,
        float* __restrict__ out) {
    __shared__ float arow[8][Cn];
    const int r0 = blockIdx.x * 8;
    const int t = threadIdx.x;
    #pragma unroll
    for (int i = 0; i < 8; ++i) arow[i][t] = A[(r0 + i) * Cn + t];
    __syncthreads();
    float acc[8] = {0.f,0.f,0.f,0.f,0.f,0.f,0.f,0.f};
    const float* wr = W + t * Cn;
    for (int k = 0; k < Cn; k += 4) {
        const float4 wv = *(const float4*)(wr + k);
        #pragma unroll
        for (int i = 0; i < 8; ++i)
            acc[i] += arow[i][k] * wv.x + arow[i][k+1] * wv.y
                    + arow[i][k+2] * wv.z + arow[i][k+3] * wv.w;
    }
    const float bv = bias ? bias[t] : 0.0f;
    #pragma unroll
    for (int i = 0; i < 8; ++i) {
        float o = acc[i] + bv;
        if (res) o += res[(r0 + i) * Cn + t];
        out[(r0 + i) * Cn + t] = o;
    }
}

// ---- 64x256 GEMM (K=256) on bf16: A from swizzled LDS tile, B(=W[j][k]) from global ----
// Per wave: 64 output cols (wid*64..+63), 4 pair-blocks x 4 j-blocks of 16x16 tiles.
static __device__ __forceinline__ void gemm64x256(
        const char* __restrict__ Abuf, const short* __restrict__ Wb,
        int wid, int lane, f32x4 acc[4][4]) {
    const int lr = lane & 15, lg = lane >> 4;
    #pragma unroll
    for (int jbp = 0; jbp < 2; ++jbp) {           // j-block pairs (B frags in regs)
        bf16x8 bfr0[8], bfr1[8];
        const int j0 = wid * 64 + jbp * 32 + lr;
        const short* w0 = Wb + j0 * 256 + lg * 8;
        const short* w1 = w0 + 16 * 256;
        #pragma unroll
        for (int kk = 0; kk < 8; ++kk) {
            bfr0[kk] = *(const bf16x8*)(w0 + kk * 32);
            bfr1[kk] = *(const bf16x8*)(w1 + kk * 32);
        }
        #pragma unroll
        for (int pb = 0; pb < 4; ++pb) {
            const int row = pb * 16 + lr;
            const int sw = (row & 7) << 4;        // XOR swizzle
            const int rb = row * 512 + lg * 16;
            #pragma unroll
            for (int kk = 0; kk < 8; ++kk) {
                bf16x8 a = *(const bf16x8*)(Abuf + ((rb + kk * 64) ^ sw));
                acc[pb][jbp * 2 + 0] = __builtin_amdgcn_mfma_f32_16x16x32_bf16(
                        a, bfr0[kk], acc[pb][jbp * 2 + 0], 0, 0, 0);
                acc[pb][jbp * 2 + 1] = __builtin_amdgcn_mfma_f32_16x16x32_bf16(
                        a, bfr1[kk], acc[pb][jbp * 2 + 1], 0, 0, 0);
            }
        }
    }
}

// ---- write accumulators (+bias, optional SiLU) back into the swizzled LDS tile ----
template <bool SILU>
static __device__ __forceinline__ void store_tiles(
        char* __restrict__ Abuf, const float* __restrict__ biasb,
        int wid, int lane, const f32x4 acc[4][4]) {
    const int lr = lane & 15, lg = lane >> 4;
    #pragma unroll
    for (int pb = 0; pb < 4; ++pb) {
        #pragma unroll
        for (int jb = 0; jb < 4; ++jb) {
            const int j = wid * 64 + (jb >> 1) * 32 + (jb & 1) * 16 + lr;
            const float bv = biasb[j];
            #pragma unroll
            for (int r = 0; r < 4; ++r) {
                const int row = pb * 16 + lg * 4 + r;   // C/D: row = 4*(lane>>4)+reg
                float hv = acc[pb][jb][r] + bv;
                if (SILU) hv = hv / (1.0f + __expf(-hv));
                *(short*)(Abuf + ((row * 512 + j * 2) ^ ((row & 7) << 4))) = f2b(hv);
            }
        }
    }
}

// ---- fused: per (b,n): loop m-tiles: emb -> MLP(P=pe) -> scores -> online softmax -> x ----
__global__ __launch_bounds__(256, 2) void fused_attn(
        const float* __restrict__ qp, const float* __restrict__ kp,
        const float* __restrict__ vp, const float* __restrict__ qpos,
        const short* __restrict__ W1b, const short* __restrict__ W2b,
        const float* __restrict__ b1, const float* __restrict__ b2,
        const float* __restrict__ freqs, float* __restrict__ xout) {
    __shared__ __align__(16) char embS[MT * 512];   // 64 x 256 bf16, XOR-swizzled; reused emb->S->P
    __shared__ float scb[MT * Hn];                  // scores, then softmax weights
    __shared__ float qbuf[Cn], b1buf[Cn], b2buf[Cn];
    __shared__ float fbuf[FHn];
    __shared__ float mxL[Hn], lL[Hn], corrL[Hn];

    const int t = threadIdx.x;
    const int lane = t & 63;
    const int wid = t >> 6;
    const int n = blockIdx.x & (Nn - 1);
    const int b = blockIdx.x >> 8;
    const int qrow = b * Nn + n;

    qbuf[t] = qp[qrow * Cn + t];
    b1buf[t] = b1[t];
    b2buf[t] = b2[t];
    if (t < FHn) fbuf[t] = freqs[t];
    if (t < Hn) { mxL[t] = -1e30f; lL[t] = 0.0f; corrL[t] = 1.0f; }

    float xacc = 0.0f;                 // thread owns output element (oh, od)
    const int oh = t >> 5, od = t & 31;
    const float* qposr = qpos + qrow * Mn;
    const f32x4 vzero = {0.0f, 0.0f, 0.0f, 0.0f};

    for (int m0 = 0; m0 < Mn; m0 += MT) {
        __syncthreads();
        // phase 1: embeddings -> embS (thread: fixed f = t&127, rows m = 2*it + (t>=128))
        {
            const int f = t & 127;
            const int mbase = t >> 7;
            const float fv = fbuf[f];
            #pragma unroll 4
            for (int it = 0; it < 32; ++it) {
                const int m = it * 2 + mbase;
                const float tv = qposr[m0 + m];
                float sv, cv;
                __sincosf(tv * fv, &sv, &cv);
                const int base = m * 512, sw = (m & 7) << 4;
                *(short*)(embS + ((base + f * 2) ^ sw)) = f2b(cv);          // emb[0:128]=cos
                *(short*)(embS + ((base + 256 + f * 2) ^ sw)) = f2b(sv);    // emb[128:256]=sin
            }
        }
        __syncthreads();
        // phase 2: GEMM1 (hidden = emb @ W1^T), acc in registers
        f32x4 acc[4][4];
        #pragma unroll
        for (int i = 0; i < 4; ++i)
            #pragma unroll
            for (int j = 0; j < 4; ++j) acc[i][j] = vzero;
        gemm64x256(embS, W1b, wid, lane, acc);
        __syncthreads();                      // all emb reads done
        store_tiles<true>(embS, b1buf, wid, lane, acc);   // S = silu(hidden+b1) -> embS
        __syncthreads();
        // phase 3: GEMM2 (P = S @ W2^T + b2)
        #pragma unroll
        for (int i = 0; i < 4; ++i)
            #pragma unroll
            for (int j = 0; j < 4; ++j) acc[i][j] = vzero;
        gemm64x256(embS, W2b, wid, lane, acc);
        __syncthreads();
        store_tiles<false>(embS, b2buf, wid, lane, acc);  // P -> embS
        __syncthreads();
        // phase 4: scores[m][h] = scale * sum_{c in head} q'_c * k'_c * P_c
        {
            const int p = t >> 2;
            const int hq = (t & 3) * 2;       // this thread: heads hq, hq+1
            const float* kr = kp + (size_t)(b * Mn + m0 + p) * Cn + hq * 32;
            const float* qr = qbuf + hq * 32;
            const int sw = (p & 7) << 4;
            const int base = p * 512 + hq * 64;
            float s0 = 0.f, s1 = 0.f;
            #pragma unroll
            for (int ch = 0; ch < 8; ++ch) {
                const bf16x8 pv = *(const bf16x8*)(embS + ((base + ch * 16) ^ sw));
                float a_ = 0.f;
                #pragma unroll
                for (int e = 0; e < 8; ++e) {
                    const int c = ch * 8 + e;
                    a_ += qr[c] * kr[c] * b2f(pv[e]);
                }
                if (ch < 4) s0 += a_; else s1 += a_;
            }
            scb[p * 8 + hq] = s0 * SCALE_;
            scb[p * 8 + hq + 1] = s1 * SCALE_;
        }
        __syncthreads();
        // phase 5: online softmax update (one thread per head)
        if (t < Hn) {
            const int h = t;
            const float mold = mxL[h];
            float tmax = -1e30f;
            for (int m = 0; m < MT; ++m) tmax = fmaxf(tmax, scb[m * 8 + h]);
            const float mnew = fmaxf(mold, tmax);
            const float corr = __expf(mold - mnew);
            float ssum = 0.f;
            for (int m = 0; m < MT; ++m) {
                const float w = __expf(scb[m * 8 + h] - mnew);
                scb[m * 8 + h] = w;
                ssum += w;
            }
            lL[h] = lL[h] * corr + ssum;
            mxL[h] = mnew;
            corrL[h] = corr;
        }
        __syncthreads();
        // phase 6: x[oh][od] accumulation over this m-tile
        {
            xacc *= corrL[oh];
            const float* vr = vp + (size_t)(b * Mn + m0) * Cn + oh * 32 + od;
            float a0 = 0.f, a1 = 0.f, a2 = 0.f, a3 = 0.f;
            for (int m = 0; m < MT; m += 4) {
                a0 += scb[(m + 0) * 8 + oh] * vr[(size_t)(m + 0) * Cn];
                a1 += scb[(m + 1) * 8 + oh] * vr[(size_t)(m + 1) * Cn];
                a2 += scb[(m + 2) * 8 + oh] * vr[(size_t)(m + 2) * Cn];
                a3 += scb[(m + 3) * 8 + oh] * vr[(size_t)(m + 3) * Cn];
            }
            xacc += (a0 + a1) + (a2 + a3);
        }
    }
    __syncthreads();
    xout[qrow * Cn + t] = xacc / lL[oh];
}

extern "C" void kernel_launch(void* const* d_in, const int* in_sizes, int n_in,
                              void* d_out, int out_size, void* d_ws, size_t ws_size,
                              hipStream_t stream) {
    const float* query = (const float*)d_in[0];
    const float* key   = (const float*)d_in[1];
    const float* qpos  = (const float*)d_in[2];
    const float* Wq    = (const float*)d_in[3];
    const float* bq    = (const float*)d_in[4];
    const float* Wk    = (const float*)d_in[5];
    const float* Wv    = (const float*)d_in[6];
    const float* bv    = (const float*)d_in[7];
    const float* Wo    = (const float*)d_in[8];
    const float* bo    = (const float*)d_in[9];
    const float* W1    = (const float*)d_in[10];
    const float* b1    = (const float*)d_in[11];
    const float* W2    = (const float*)d_in[12];
    const float* b2    = (const float*)d_in[13];
    const float* freqs = (const float*)d_in[14];
    float* out = (float*)d_out;

    char* ws = (char*)d_ws;
    float* qp  = (float*)(ws);                 // 512 KB  (B*N*C f32)
    float* kp  = (float*)(ws + 524288);        // 1 MB    (B*M*C f32)
    float* vp  = (float*)(ws + 1572864);       // 1 MB
    float* xo  = (float*)(ws + 2621440);       // 512 KB
    short* W1b = (short*)(ws + 3145728);       // 128 KB bf16
    short* W2b = (short*)(ws + 3276800);       // 128 KB bf16

    convert_w<<<256, 256, 0, stream>>>(W1, W2, W1b, W2b);
    linear8<<<64, 256, 0, stream>>>(query, Wq, bq, nullptr, qp);    // q' (512 rows)
    linear8<<<128, 256, 0, stream>>>(key, Wk, nullptr, nullptr, kp); // k' (1024 rows, no bias)
    linear8<<<128, 256, 0, stream>>>(key, Wv, bv, nullptr, vp);      // v'
    fused_attn<<<Bn * Nn, 256, 0, stream>>>(qp, kp, vp, qpos, W1b, W2b, b1, b2, freqs, xo);
    linear8<<<64, 256, 0, stream>>>(xo, Wo, bo, query, out);         // out = x@Wo^T+bo+query
}